// Round 11
// baseline (429.742 us; speedup 1.0000x reference)
//
#include <hip/hip_runtime.h>
#include <float.h>
#include <math.h>

// ---------------------------------------------------------------------------
// UltraMemLayerV1 — round 11:
//  (a) s_r stored as bf16 (prefilter is bf16-precision anyway); topk1 does a
//      16-step u16-key bisection on contiguous ushort loads.
//  (b) q GEMM stages A from natural hidden[M][K] (8-VGPR reg hold + LDS
//      scatter); hiddenT transpose kernel removed.
//  (c) k_sel2 fuses exact-rescore + exact top-32 (both sides) + stage-2
//      bilinear/top-32/set-softmax into one 512-thread kernel per (b,h).
// ---------------------------------------------------------------------------

typedef __attribute__((ext_vector_type(8))) __bf16 bf16x8;
typedef __attribute__((ext_vector_type(4))) float f32x4;

__device__ __forceinline__ unsigned short f2bf(float x) {
  unsigned int u = __float_as_uint(x);
  return (unsigned short)((u + 0x7FFFu + ((u >> 16) & 1u)) >> 16);
}

__device__ __forceinline__ float wave_sum(float x) {
#pragma unroll
  for (int o = 32; o; o >>= 1) x += __shfl_xor(x, o, 64);
  return x;
}

__device__ __forceinline__ void gll16(const float* g, float* l) {
  __builtin_amdgcn_global_load_lds(
      (const __attribute__((address_space(1))) void*)g,
      (__attribute__((address_space(3))) void*)l, 16, 0, 0);
}

// monotone f32 -> u32 key (order-preserving) and inverse
__device__ __forceinline__ unsigned int f2key(float f) {
  const unsigned int u = __float_as_uint(f);
  return u ^ (((unsigned int)((int)u >> 31)) | 0x80000000u);
}
__device__ __forceinline__ float key2f(unsigned int k) {
  return __uint_as_float((k & 0x80000000u) ? (k ^ 0x80000000u) : ~k);
}

// ---------------- keys prep: LN, fold knorm + tucker u/v; bf16 Bct ----------
__global__ void k_prep32(const float* __restrict__ keys, const float* __restrict__ knw,
                         const float* __restrict__ tu, const float* __restrict__ tv,
                         unsigned short* __restrict__ Bctbf, float* __restrict__ Bg) {
  const int bid = blockIdx.x;  // 4096 = c*2048 + h*1024 + k
  const int lane = threadIdx.x;
  const int k = bid & 1023, h = (bid >> 10) & 1, c = bid >> 11;
  const float* base = keys + (size_t)((h * 2 + c) * 1024 + k) * 512;  // (h,c,k,d,r)
  float x0[4], x1[4];
  float s0 = 0.f, s1 = 0.f, sq0 = 0.f, sq1 = 0.f;
#pragma unroll
  for (int i = 0; i < 4; ++i) {
    const int d = lane + i * 64;
    const float2 p = *(const float2*)&base[d * 2];
    x0[i] = p.x; x1[i] = p.y;
    s0 += p.x; sq0 += p.x * p.x;
    s1 += p.y; sq1 += p.y * p.y;
  }
  s0 = wave_sum(s0); sq0 = wave_sum(sq0);
  s1 = wave_sum(s1); sq1 = wave_sum(sq1);
  const float m0 = s0 * (1.f / 256.f), m1 = s1 * (1.f / 256.f);
  const float rs0 = 1.f / sqrtf(sq0 * (1.f / 256.f) - m0 * m0 + 1e-5f);
  const float rs1 = 1.f / sqrtf(sq1 * (1.f / 256.f) - m1 * m1 + 1e-5f);
  const float* uv = c ? tv : tu;
  const float u0 = uv[h * 2 + 0], u1 = uv[h * 2 + 1];
  const int chk = c * 2048 + h * 1024 + k;
  float* bg = Bg + (size_t)chk * 512;
  unsigned short* bc = Bctbf + (size_t)chk * 256;
#pragma unroll
  for (int i = 0; i < 4; ++i) {
    const int d = lane + i * 64;
    const float w = knw[d];
    const float y0 = (x0[i] - m0) * rs0 * w;
    const float y1 = (x1[i] - m1) * rs1 * w;
    bg[d] = y0;
    bg[256 + d] = y1;
    bc[d] = f2bf(y0 * u0 + y1 * u1);
  }
}

// ---------------- q GEMM: hidden[M][K] @ wq[K][N], split-K=4 ----------------
// A staged via 2x float4 register hold + LDS transpose-scatter (8 VGPRs);
// B staged via global_load_lds. 2-phase prefetch, double-buffered LDS.
__global__ __launch_bounds__(256) void k_qgemm(const float* __restrict__ A,
                                               const float* __restrict__ B,
                                               float* __restrict__ C) {
  constexpr int BK = 16;
  constexpr int K = 2048, N = 512;
  __shared__ float As[2][BK][128];
  __shared__ float Bs[2][BK][128];
  const int tid = threadIdx.x;
  const int lane = tid & 63;
  const int w = tid >> 6;
  const int tx = tid & 15, ty = tid >> 4;
  const int bm = blockIdx.x * 128, bn = blockIdx.y * 128;
  const int kbeg = blockIdx.z * 512;
  float* Cp = C + (size_t)blockIdx.z * 4096 * 512;
  const int l5 = lane >> 5, l31 = lane & 31;
  float acc[8][8] = {};
  float4 ar[2];

  auto regloadA = [&](int t) {
    const int k0 = kbeg + t * BK;
#pragma unroll
    for (int u = 0; u < 2; ++u) {
      const int q = tid + u * 256;
      const int m = q >> 2, kc = q & 3;
      ar[u] = *(const float4*)&A[(size_t)(bm + m) * K + k0 + kc * 4];
    }
  };
  auto dswriteA = [&](int buf) {
#pragma unroll
    for (int u = 0; u < 2; ++u) {
      const int q = tid + u * 256;
      const int m = q >> 2, kc = q & 3;
      As[buf][kc * 4 + 0][m] = ar[u].x;
      As[buf][kc * 4 + 1][m] = ar[u].y;
      As[buf][kc * 4 + 2][m] = ar[u].z;
      As[buf][kc * 4 + 3][m] = ar[u].w;
    }
  };
  auto stageB = [&](int buf, int t) {
    const int k0 = kbeg + t * BK;
#pragma unroll
    for (int i = 0; i < 2; ++i) {
      const int rr = w * 4 + i * 2;
      const size_t krow = (size_t)(k0 + rr + l5);
      gll16(&B[krow * N + bn + l31 * 4], &Bs[buf][rr][0]);
    }
  };

  regloadA(0);
  stageB(0, 0);
  dswriteA(0);
  __syncthreads();
  int cur = 0;
  const int T = 512 / BK;
  for (int t = 0; t < T; ++t) {
    if (t + 1 < T) {
      regloadA(t + 1);         // global loads hide under compute
      stageB(cur ^ 1, t + 1);  // async B prefetch
    }
#pragma unroll
    for (int kk = 0; kk < BK; ++kk) {
      float a[8], b[8];
      *(float4*)&a[0] = *(const float4*)&As[cur][kk][ty * 4];
      *(float4*)&a[4] = *(const float4*)&As[cur][kk][64 + ty * 4];
      *(float4*)&b[0] = *(const float4*)&Bs[cur][kk][tx * 4];
      *(float4*)&b[4] = *(const float4*)&Bs[cur][kk][64 + tx * 4];
#pragma unroll
      for (int i = 0; i < 8; ++i)
#pragma unroll
        for (int j = 0; j < 8; ++j) acc[i][j] += a[i] * b[j];
    }
    if (t + 1 < T) dswriteA(cur ^ 1);
    __syncthreads();
    cur ^= 1;
  }
#pragma unroll
  for (int ih = 0; ih < 2; ++ih)
#pragma unroll
    for (int i = 0; i < 4; ++i) {
      const size_t r = bm + ih * 64 + ty * 4 + i;
#pragma unroll
      for (int jh = 0; jh < 2; ++jh) {
        float4 v = {acc[ih * 4 + i][jh * 4 + 0], acc[ih * 4 + i][jh * 4 + 1],
                    acc[ih * 4 + i][jh * 4 + 2], acc[ih * 4 + i][jh * 4 + 3]};
        *(float4*)&Cp[r * N + bn + jh * 64 + tx * 4] = v;
      }
    }
}

// ---------------- q: sum split-K partials (4) + LN -> q12n (f32 + bf16) -----
__global__ void k_ln_q(const float* __restrict__ qpart, const float* __restrict__ qnw,
                       float* __restrict__ q12n, unsigned short* __restrict__ q12bf) {
  const int bid = blockIdx.x;  // b*2 + c
  const int lane = threadIdx.x;
  const int b = bid >> 1, c = bid & 1;
  float x[4] = {};
#pragma unroll
  for (int s = 0; s < 4; ++s) {
    const float4 p = *(const float4*)&qpart[(size_t)s * 4096 * 512 + (size_t)b * 512 + c * 256 + lane * 4];
    x[0] += p.x; x[1] += p.y; x[2] += p.z; x[3] += p.w;
  }
  float sm = x[0] + x[1] + x[2] + x[3];
  float sq = x[0] * x[0] + x[1] * x[1] + x[2] * x[2] + x[3] * x[3];
  sm = wave_sum(sm);
  sq = wave_sum(sq);
  const float mean = sm * (1.f / 256.f);
  const float rs = 1.f / sqrtf(sq * (1.f / 256.f) - mean * mean + 1e-5f);
  const float4 w4 = *(const float4*)&qnw[lane * 4];
  float4 o;
  o.x = (x[0] - mean) * rs * w4.x;
  o.y = (x[1] - mean) * rs * w4.y;
  o.z = (x[2] - mean) * rs * w4.z;
  o.w = (x[3] - mean) * rs * w4.w;
  const size_t base = (size_t)(c * 4096 + b) * 256 + lane * 4;
  *(float4*)&q12n[base] = o;
  ushort4 ob;
  ob.x = f2bf(o.x); ob.y = f2bf(o.y); ob.z = f2bf(o.z); ob.w = f2bf(o.w);
  *(ushort4*)&q12bf[base] = ob;
}

// ---------------- stage-1 top-48 prefilter on bf16 scores (16-bit keys) -----
__global__ void k_topk1(const unsigned short* __restrict__ s_r,
                        int* __restrict__ i1c, int* __restrict__ i2c) {
  const int bid = blockIdx.x;  // side*8192 + b*2 + h
  const int side = bid >> 13;
  const int bh = bid & 8191;
  const int b = bh >> 1, h = bh & 1;
  const int lane = threadIdx.x;
  const unsigned short* row = s_r + (size_t)(side * 4096 + b) * 2048 + h * 1024;
  unsigned int ku[16];
  {
    const uint4 a = *(const uint4*)&row[lane * 16];
    const uint4 bq = *(const uint4*)&row[lane * 16 + 8];
    const unsigned int words[8] = {a.x, a.y, a.z, a.w, bq.x, bq.y, bq.z, bq.w};
#pragma unroll
    for (int j = 0; j < 8; ++j) {
      const unsigned int lo = words[j] & 0xFFFFu;
      const unsigned int hi = words[j] >> 16;
      ku[2 * j] = lo ^ ((lo & 0x8000u) ? 0xFFFFu : 0x8000u);
      ku[2 * j + 1] = hi ^ ((hi & 0x8000u) ? 0xFFFFu : 0x8000u);
    }
  }
  unsigned int T = 0u;
  for (int bpos = 15; bpos >= 0; --bpos) {
    const unsigned int cand = T | (1u << bpos);
    int c = 0;
#pragma unroll
    for (int i = 0; i < 16; ++i) c += (int)__popcll(__ballot(ku[i] >= cand));
    if (c >= 48) T = cand;  // uniform
  }
  int cgt = 0, ceq = 0;
#pragma unroll
  for (int i = 0; i < 16; ++i) {
    cgt += (ku[i] > T) ? 1 : 0;
    ceq += (ku[i] == T) ? 1 : 0;
  }
  int pgt = cgt, peq = ceq;
#pragma unroll
  for (int o = 1; o < 64; o <<= 1) {
    const int t1 = __shfl_up(pgt, o, 64);
    const int t2 = __shfl_up(peq, o, 64);
    if (lane >= o) { pgt += t1; peq += t2; }
  }
  const int total_gt = __shfl(pgt, 63, 64);  // < 48
  const int need_eq = 48 - total_gt;
  int sgt = pgt - cgt;
  int seq = peq - ceq;
  int* iout = (side ? i2c : i1c) + bh * 48;
#pragma unroll
  for (int i = 0; i < 16; ++i) {
    const int idx = lane * 16 + i;
    if (ku[i] > T) {
      iout[sgt++] = idx;
    } else if (ku[i] == T) {
      if (seq < need_eq) iout[total_gt + seq] = idx;
      ++seq;
    }
  }
}

// ---------------- fused: exact rescore (48x2 sides) + top-32 + stage-2 ------
// 512 threads per (b,h). Waves 0-2: side-0 dots; waves 4-6: side-1 dots
// (line-dense Bg reads). Wave 0/4: exact f32 top-32 via single-ballot
// bisection. Wave 0 tail: 32x32 tucker bilinear, top-32, set-softmax,
// shuffle lookup -> wgt/sho.
__global__ __launch_bounds__(512) void k_sel2(
    const float* __restrict__ q12n, const float* __restrict__ Bg,
    const int* __restrict__ i1c, const int* __restrict__ i2c,
    const float* __restrict__ tu, const float* __restrict__ tv,
    const float* __restrict__ tucker_core, const int* __restrict__ shuffle_index,
    float* __restrict__ w_out, int* __restrict__ sh_out) {
  __shared__ float qs[2][256];
  __shared__ int ssel[2][48];
  __shared__ float sc[2][48], sd0s[2][48], sd1s[2][48];
  __shared__ float sgx[2][32], sgy[2][32];
  __shared__ int si32[2][32];
  const int bh = blockIdx.x;  // b*2 + h
  const int b = bh >> 1, h = bh & 1;
  const int tid = threadIdx.x;
  if (tid < 128) {
    const int sd = tid >> 6, t = tid & 63;
    *(float4*)&qs[sd][t * 4] =
        *(const float4*)&q12n[(size_t)(sd * 4096 + b) * 256 + t * 4];
  } else if (tid < 224) {
    const int j = tid - 128;  // 0..95
    const int sd = (j >= 48) ? 1 : 0;
    const int jj = j - sd * 48;
    ssel[sd][jj] = (sd ? i2c : i1c)[bh * 48 + jj];
  }
  __syncthreads();
  const int w = tid >> 6;
  const int sd = (w >= 4) ? 1 : 0;
  const int local = tid - sd * 256;
  const int g = local >> 2, c4 = local & 3;
  if (g < 48) {
    const int sel = ssel[sd][g];
    const float* kbase = Bg + (size_t)((sd * 2048 + h * 1024 + sel) * 2) * 256;
    const float* qp = qs[sd];
    float d0 = 0.f, d1 = 0.f;
#pragma unroll
    for (int r = 0; r < 2; ++r) {
      const float* krow = kbase + r * 256;
      float px = 0.f, py = 0.f, pz = 0.f, pw = 0.f;
#pragma unroll
      for (int i = 0; i < 16; ++i) {
        const int e = (i * 4 + c4) * 4;  // 4-lane group covers one 64B line
        const float4 kv = *(const float4*)&krow[e];
        const float4 qv = *(const float4*)&qp[e];
        px += kv.x * qv.x;
        py += kv.y * qv.y;
        pz += kv.z * qv.z;
        pw += kv.w * qv.w;
      }
      float a = (px + py) + (pz + pw);
      a += __shfl_xor(a, 1, 64);
      a += __shfl_xor(a, 2, 64);
      if (r == 0) d0 = a; else d1 = a;
    }
    if (c4 == 0) {
      const float* uv = sd ? tv : tu;
      sd0s[sd][g] = d0;
      sd1s[sd][g] = d1;
      sc[sd][g] = d0 * uv[h * 2 + 0] + d1 * uv[h * 2 + 1];
    }
  }
  __syncthreads();
  if (w == 0 || w == 4) {
    const int s2 = (w == 4) ? 1 : 0;
    const int lane = tid & 63;
    const unsigned int kv = (lane < 48) ? f2key(sc[s2][lane]) : 0u;
    unsigned int T = 0u;
    for (int bpos = 31; bpos >= 0; --bpos) {
      const unsigned int cand = T | (1u << bpos);
      if ((int)__popcll(__ballot(kv >= cand)) >= 32) T = cand;
    }
    const unsigned long long mgt = __ballot(kv > T);
    const unsigned long long meq = __ballot((kv == T) && (lane < 48));
    const unsigned long long below = ((unsigned long long)1 << lane) - 1;
    const int total_gt = (int)__popcll(mgt);
    const int need = 32 - total_gt;
    int slot = -1;
    if (kv > T) {
      slot = (int)__popcll(mgt & below);
    } else if (kv == T && lane < 48) {
      const int r = (int)__popcll(meq & below);
      if (r < need) slot = total_gt + r;
    }
    if (slot >= 0) {
      si32[s2][slot] = ssel[s2][lane];
      sgx[s2][slot] = sd0s[s2][lane];
      sgy[s2][slot] = sd1s[s2][lane];
    }
  }
  __syncthreads();
  if (w == 0) {
    const int lane = tid;  // 0..63
    const float c00 = tucker_core[h * 4 + 0] + tucker_core[8 + h * 4 + 0];
    const float c01 = tucker_core[h * 4 + 1] + tucker_core[8 + h * 4 + 1];
    const float c10 = tucker_core[h * 4 + 2] + tucker_core[8 + h * 4 + 2];
    const float c11 = tucker_core[h * 4 + 3] + tucker_core[8 + h * 4 + 3];
    float sv[16];
    unsigned int ku[16];
    float m = -FLT_MAX;
#pragma unroll
    for (int i = 0; i < 16; ++i) {
      const int p = lane + (i << 6);
      const int k = p >> 5, l = p & 31;
      const float a0 = sgx[0][k] * c00 + sgy[0][k] * c10;
      const float a1 = sgx[0][k] * c01 + sgy[0][k] * c11;
      sv[i] = a0 * sgx[1][l] + a1 * sgy[1][l];
      ku[i] = f2key(sv[i]);
      m = fmaxf(m, sv[i]);
    }
#pragma unroll
    for (int o = 32; o; o >>= 1) m = fmaxf(m, __shfl_xor(m, o, 64));
    unsigned int T = 0u;
    for (int bpos = 31; bpos >= 0; --bpos) {
      const unsigned int cand = T | (1u << bpos);
      int c = 0;
#pragma unroll
      for (int i = 0; i < 16; ++i) c += (int)__popcll(__ballot(ku[i] >= cand));
      if (c >= 32) T = cand;
    }
    int cgt = 0, ceq = 0;
    float zp = 0.f;
#pragma unroll
    for (int i = 0; i < 16; ++i) {
      if (ku[i] > T) { ++cgt; zp += expf(sv[i] - m); }
      ceq += (ku[i] == T) ? 1 : 0;
    }
    int pgt = cgt, peq = ceq;
#pragma unroll
    for (int o = 1; o < 64; o <<= 1) {
      const int t1 = __shfl_up(pgt, o, 64);
      const int t2 = __shfl_up(peq, o, 64);
      if (lane >= o) { pgt += t1; peq += t2; }
    }
    const int total_gt = __shfl(pgt, 63, 64);
    const int need_eq = 32 - total_gt;
    const float eT = expf(key2f(T) - m);
    const float Z = wave_sum(zp) + (float)need_eq * eT;
    const float rZ = 1.f / Z;
    int sgt = pgt - cgt;
    int seq = peq - ceq;
    float* wp = w_out + bh * 32;
    int* shp = sh_out + bh * 32;
#pragma unroll
    for (int i = 0; i < 16; ++i) {
      int slot = -1;
      if (ku[i] > T) {
        slot = sgt++;
      } else if (ku[i] == T) {
        if (seq < need_eq) slot = total_gt + seq;
        ++seq;
      }
      if (slot >= 0) {
        const int p = lane + (i << 6);
        const int k = p >> 5, l = p & 31;
        const int ai = si32[0][k] * 1024 + si32[1][l];
        wp[slot] = expf(sv[i] - m) * rZ;
        shp[slot] = shuffle_index[ai];  // = (eidx<<18) | vidx
      }
    }
  }
}

// ---------------- weighted value gather/aggregate -> bf16 agg ---------------
__global__ __launch_bounds__(256) void k_agg(const float* __restrict__ w_out,
                                             const int* __restrict__ sh_out,
                                             const float* __restrict__ values,
                                             unsigned short* __restrict__ aggb) {
  __shared__ float acc[4][1024];
  const int b = blockIdx.x;
  const int tid = threadIdx.x;
  const int wave = tid >> 6, lane = tid & 63;
  for (int i = tid; i < 4096; i += 256) ((float*)acc)[i] = 0.f;
  __syncthreads();
  for (int j = wave; j < 64; j += 4) {
    const float wgt = w_out[b * 64 + j];
    const int sh = sh_out[b * 64 + j];
    const int vidx = sh & 0x3FFFF;
    const int e = sh >> 18;
    const float4 v = *(const float4*)&values[(size_t)vidx * 256 + lane * 4];
    float* dst = &acc[wave][e * 256 + lane * 4];
    dst[0] += wgt * v.x;
    dst[1] += wgt * v.y;
    dst[2] += wgt * v.z;
    dst[3] += wgt * v.w;
  }
  __syncthreads();
  for (int i = tid; i < 1024; i += 256)
    aggb[(size_t)b * 1024 + i] = f2bf(acc[0][i] + acc[1][i] + acc[2][i] + acc[3][i]);
}

// ---------------- transpose + convert f32 -> bf16 (for wv) ------------------
__global__ __launch_bounds__(256) void k_tcvt(const float* __restrict__ src,
                                              unsigned short* __restrict__ dst,
                                              int R, int C) {
  __shared__ float tile[64][65];
  const int br = blockIdx.x * 64;
  const int bc = blockIdx.y * 64;
  const int tid = threadIdx.x;
  for (int idx = tid; idx < 4096; idx += 256) {
    const int r = idx >> 6, c = idx & 63;
    tile[r][c] = src[(size_t)(br + r) * C + bc + c];
  }
  __syncthreads();
  for (int idx = tid; idx < 4096; idx += 256) {
    const int cc = idx >> 6, rr = idx & 63;
    dst[(size_t)(bc + cc) * R + br + rr] = f2bf(tile[rr][cc]);
  }
}

// ---------------- bf16 MFMA GEMM (scores -> bf16 out; final -> f32 out) -----
// C[M][N] = A[M][K] @ Bt[N][K]^T; B-column offset bsk applied for rows >=
// m_split (fused two-sided score GEMM).
template <int BM, int BN, bool OBF>
__global__ __launch_bounds__(256) void k_mfma(const unsigned short* __restrict__ A,
                                              const unsigned short* __restrict__ Bt,
                                              void* __restrict__ Cv,
                                              int M, int N, int K,
                                              int bsk, int m_split) {
  constexpr int FM = BM / 32;
  constexpr int FN = BN / 32;
  __shared__ float4 As[BM * 4];
  __shared__ float4 Bs[BN * 4];
  const int tid = threadIdx.x;
  const int lane = tid & 63;
  const int w = tid >> 6;
  const int wr = w >> 1, wc = w & 1;
  const int bm = blockIdx.x * BM, bn = blockIdx.y * BN;
  const int bcol = bn + ((bm >= m_split) ? bsk : 0);
  f32x4 acc[FM][FN];
#pragma unroll
  for (int i = 0; i < FM; ++i)
#pragma unroll
    for (int j = 0; j < FN; ++j) acc[i][j] = 0.f;

  for (int k0 = 0; k0 < K; k0 += 32) {
#pragma unroll
    for (int u = 0; u < BM * 4 / 256; ++u) {
      const int q = tid + u * 256;
      const int m = q >> 2, c = q & 3;
      As[(m >> 4) * 64 + c * 16 + (m & 15)] =
          *(const float4*)&A[(size_t)(bm + m) * K + k0 + c * 8];
    }
#pragma unroll
    for (int u = 0; u < BN * 4 / 256; ++u) {
      const int q = tid + u * 256;
      const int n = q >> 2, c = q & 3;
      Bs[(n >> 4) * 64 + c * 16 + (n & 15)] =
          *(const float4*)&Bt[(size_t)(bcol + n) * K + k0 + c * 8];
    }
    __syncthreads();
    bf16x8 af[FM], bfr[FN];
#pragma unroll
    for (int i = 0; i < FM; ++i) af[i] = *(const bf16x8*)&As[(wr * FM + i) * 64 + lane];
#pragma unroll
    for (int j = 0; j < FN; ++j) bfr[j] = *(const bf16x8*)&Bs[(wc * FN + j) * 64 + lane];
#pragma unroll
    for (int i = 0; i < FM; ++i)
#pragma unroll
      for (int j = 0; j < FN; ++j)
        acc[i][j] = __builtin_amdgcn_mfma_f32_16x16x32_bf16(af[i], bfr[j], acc[i][j], 0, 0, 0);
    __syncthreads();
  }
#pragma unroll
  for (int i = 0; i < FM; ++i) {
    const int r0 = bm + (wr * FM + i) * 16 + (lane >> 4) * 4;
#pragma unroll
    for (int j = 0; j < FN; ++j) {
      const int cc = bn + (wc * FN + j) * 16 + (lane & 15);
#pragma unroll
      for (int v = 0; v < 4; ++v) {
        if (OBF)
          ((unsigned short*)Cv)[(size_t)(r0 + v) * N + cc] = f2bf(acc[i][j][v]);
        else
          ((float*)Cv)[(size_t)(r0 + v) * N + cc] = acc[i][j][v];
      }
    }
  }
}

// ---------------------------------------------------------------------------
extern "C" void kernel_launch(void* const* d_in, const int* in_sizes, int n_in,
                              void* d_out, int out_size, void* d_ws, size_t ws_size,
                              hipStream_t stream) {
  const float* hidden = (const float*)d_in[0];
  const float* wq     = (const float*)d_in[1];
  const float* qnw    = (const float*)d_in[2];
  const float* knw    = (const float*)d_in[3];
  const float* keys   = (const float*)d_in[4];
  const float* tcore  = (const float*)d_in[5];
  const float* tu     = (const float*)d_in[6];
  const float* tv     = (const float*)d_in[7];
  const float* values = (const float*)d_in[8];
  const float* wvm    = (const float*)d_in[9];
  const int*   shuf   = (const int*)d_in[10];
  float* out = (float*)d_out;

  char* ws = (char*)d_ws;
  size_t off = 0;
  auto alloc = [&](size_t bytes) -> void* {
    void* p = ws + off;
    off += (bytes + 255) & ~(size_t)255;
    return p;
  };
  unsigned short* Bctbf = (unsigned short*)alloc((size_t)4096 * 256 * 2);  // 2 MB
  float* Bg    = (float*)alloc((size_t)4096 * 512 * 4);                    // 8 MB
  float* q12n  = (float*)alloc((size_t)8192 * 256 * 4);                    // 8 MB
  unsigned short* q12bf = (unsigned short*)alloc((size_t)8192 * 256 * 2);  // 4 MB
  unsigned short* wvT  = (unsigned short*)alloc((size_t)2048 * 1024 * 2);  // 4 MB
  unsigned short* aggb = (unsigned short*)alloc((size_t)4096 * 1024 * 2);  // 8 MB
  int*   i1c = (int*)  alloc((size_t)8192 * 48 * 4);
  int*   i2c = (int*)  alloc((size_t)8192 * 48 * 4);
  float* wgt = (float*)alloc((size_t)8192 * 32 * 4);
  int*   sho = (int*)  alloc((size_t)8192 * 32 * 4);
  float* big = (float*)alloc((size_t)8192 * 2048 * 4);  // 64 MB shared region
  float* qpart = big;                       // 4 x 4096 x 512 f32 (32 MB), dead after ln_q
  unsigned short* s_r = (unsigned short*)big;  // 8192 x 2048 bf16 (32 MB), written after
  (void)ws_size; (void)in_sizes; (void)n_in; (void)out_size;

  // 1) keys -> Bg (raw keysn, f32) + Bctbf (u/v-combined, bf16)
  k_prep32<<<4096, 64, 0, stream>>>(keys, knw, tu, tv, Bctbf, Bg);
  // 2) wv -> bf16 transposed
  k_tcvt<<<dim3(16, 32), 256, 0, stream>>>(wvm, wvT, 1024, 2048);
  // 3) q projection, f32 split-K=4 (A staged from natural hidden layout)
  k_qgemm<<<dim3(32, 4, 4), 256, 0, stream>>>(hidden, wq, qpart);
  // 4) sum partials + LN -> q12n (f32) + q12bf (bf16)
  k_ln_q<<<8192, 64, 0, stream>>>(qpart, qnw, q12n, q12bf);
  // 5) prefilter score GEMM (bf16 MFMA, bf16 output)
  k_mfma<128, 128, true><<<dim3(64, 16), 256, 0, stream>>>(
      q12bf, Bctbf, s_r, 8192, 2048, 256, 2048, 4096);
  // 6) stage-1 top-48 prefilter (16-bit bisection)
  k_topk1<<<16384, 64, 0, stream>>>(s_r, i1c, i2c);
  // 7) fused exact rescore + top-32 + stage-2 -> wgt/sho
  k_sel2<<<8192, 512, 0, stream>>>(q12n, Bg, i1c, i2c, tu, tv, tcore, shuf,
                                   wgt, sho);
  // 8) weighted value gather -> bf16 agg
  k_agg<<<4096, 256, 0, stream>>>(wgt, sho, values, aggb);
  // 9) output projection (bf16 MFMA, f32 output)
  k_mfma<128, 128, false><<<dim3(32, 16), 256, 0, stream>>>(
      aggb, wvT, out, 4096, 2048, 1024, 0, 1 << 30);
}

// Round 12
// 401.385 us; speedup vs baseline: 1.0706x; 1.0706x over previous
//
#include <hip/hip_runtime.h>
#include <float.h>
#include <math.h>

// ---------------------------------------------------------------------------
// UltraMemLayerV1 — round 12: revert q-GEMM fusion (round-11 regression:
// k_qgemm held A-staging regs across the FMA loop -> VGPR 180, occ 11%,
// 185us vs 97us for tr32+gemm32). Back to round-10's separate transpose +
// k_gemm32. KEEP round-11 wins: bf16 s_r + 16-bit topk1, fused k_sel2.
// ---------------------------------------------------------------------------

typedef __attribute__((ext_vector_type(8))) __bf16 bf16x8;
typedef __attribute__((ext_vector_type(4))) float f32x4;

__device__ __forceinline__ unsigned short f2bf(float x) {
  unsigned int u = __float_as_uint(x);
  return (unsigned short)((u + 0x7FFFu + ((u >> 16) & 1u)) >> 16);
}

__device__ __forceinline__ float wave_sum(float x) {
#pragma unroll
  for (int o = 32; o; o >>= 1) x += __shfl_xor(x, o, 64);
  return x;
}

__device__ __forceinline__ void gll16(const float* g, float* l) {
  __builtin_amdgcn_global_load_lds(
      (const __attribute__((address_space(1))) void*)g,
      (__attribute__((address_space(3))) void*)l, 16, 0, 0);
}

// monotone f32 -> u32 key (order-preserving) and inverse
__device__ __forceinline__ unsigned int f2key(float f) {
  const unsigned int u = __float_as_uint(f);
  return u ^ (((unsigned int)((int)u >> 31)) | 0x80000000u);
}
__device__ __forceinline__ float key2f(unsigned int k) {
  return __uint_as_float((k & 0x80000000u) ? (k ^ 0x80000000u) : ~k);
}

// ---------------- keys prep: LN, fold knorm + tucker u/v; bf16 Bct ----------
__global__ void k_prep32(const float* __restrict__ keys, const float* __restrict__ knw,
                         const float* __restrict__ tu, const float* __restrict__ tv,
                         unsigned short* __restrict__ Bctbf, float* __restrict__ Bg) {
  const int bid = blockIdx.x;  // 4096 = c*2048 + h*1024 + k
  const int lane = threadIdx.x;
  const int k = bid & 1023, h = (bid >> 10) & 1, c = bid >> 11;
  const float* base = keys + (size_t)((h * 2 + c) * 1024 + k) * 512;  // (h,c,k,d,r)
  float x0[4], x1[4];
  float s0 = 0.f, s1 = 0.f, sq0 = 0.f, sq1 = 0.f;
#pragma unroll
  for (int i = 0; i < 4; ++i) {
    const int d = lane + i * 64;
    const float2 p = *(const float2*)&base[d * 2];
    x0[i] = p.x; x1[i] = p.y;
    s0 += p.x; sq0 += p.x * p.x;
    s1 += p.y; sq1 += p.y * p.y;
  }
  s0 = wave_sum(s0); sq0 = wave_sum(sq0);
  s1 = wave_sum(s1); sq1 = wave_sum(sq1);
  const float m0 = s0 * (1.f / 256.f), m1 = s1 * (1.f / 256.f);
  const float rs0 = 1.f / sqrtf(sq0 * (1.f / 256.f) - m0 * m0 + 1e-5f);
  const float rs1 = 1.f / sqrtf(sq1 * (1.f / 256.f) - m1 * m1 + 1e-5f);
  const float* uv = c ? tv : tu;
  const float u0 = uv[h * 2 + 0], u1 = uv[h * 2 + 1];
  const int chk = c * 2048 + h * 1024 + k;
  float* bg = Bg + (size_t)chk * 512;
  unsigned short* bc = Bctbf + (size_t)chk * 256;
#pragma unroll
  for (int i = 0; i < 4; ++i) {
    const int d = lane + i * 64;
    const float w = knw[d];
    const float y0 = (x0[i] - m0) * rs0 * w;
    const float y1 = (x1[i] - m1) * rs1 * w;
    bg[d] = y0;
    bg[256 + d] = y1;
    bc[d] = f2bf(y0 * u0 + y1 * u1);
  }
}

// ---------------- f32 transpose: src[R][C] -> dst[C][R] ---------------------
__global__ __launch_bounds__(256) void k_tr32(const float* __restrict__ src,
                                              float* __restrict__ dst, int R, int C) {
  __shared__ float t[64][65];
  const int br = blockIdx.x * 64, bc = blockIdx.y * 64;
  const int tid = threadIdx.x;
  for (int idx = tid; idx < 4096; idx += 256) {
    const int r = idx >> 6, c = idx & 63;
    t[r][c] = src[(size_t)(br + r) * C + bc + c];
  }
  __syncthreads();
  for (int idx = tid; idx < 4096; idx += 256) {
    const int cc = idx >> 6, rr = idx & 63;
    dst[(size_t)(bc + cc) * R + br + rr] = t[rr][cc];
  }
}

// ---------------- f32 GEMM, [K][*] operands, 2-phase prefetch dbuf ----------
template <int SPLITK>
__global__ __launch_bounds__(256) void k_gemm32(
    const float* __restrict__ AT, int lda,
    const float* __restrict__ BT, int ldb, int bsk, int m_split,
    float* __restrict__ C, int M, int N, int K) {
  constexpr int BK = 16;
  __shared__ float As[2][BK][128];
  __shared__ float Bs[2][BK][128];
  const int tid = threadIdx.x;
  const int lane = tid & 63;
  const int w = tid >> 6;
  const int tx = tid & 15, ty = tid >> 4;
  const int bm = blockIdx.x * 128, bn = blockIdx.y * 128;
  const int bcol = bn + ((bm >= m_split) ? bsk : 0);
  const int Ks = K / SPLITK;
  const int kbeg = blockIdx.z * Ks;
  float* Cp = C + (size_t)blockIdx.z * M * N;
  const int l5 = lane >> 5, l31 = lane & 31;
  float acc[8][8] = {};

  auto stage = [&](int buf, int t) {
    const int k0 = t * BK;
#pragma unroll
    for (int i = 0; i < 2; ++i) {
      const int rr = w * 4 + i * 2;
      const size_t krow = (size_t)(kbeg + k0 + rr + l5);
      gll16(&AT[krow * lda + bm + l31 * 4], &As[buf][rr][0]);
      gll16(&BT[krow * ldb + bcol + l31 * 4], &Bs[buf][rr][0]);
    }
  };

  const int T = Ks / BK;
  stage(0, 0);
  __syncthreads();
  int cur = 0;
  for (int t = 0; t < T; ++t) {
    if (t + 1 < T) stage(cur ^ 1, t + 1);  // prefetch under compute
#pragma unroll
    for (int kk = 0; kk < BK; ++kk) {
      float a[8], b[8];
      *(float4*)&a[0] = *(const float4*)&As[cur][kk][ty * 4];
      *(float4*)&a[4] = *(const float4*)&As[cur][kk][64 + ty * 4];
      *(float4*)&b[0] = *(const float4*)&Bs[cur][kk][tx * 4];
      *(float4*)&b[4] = *(const float4*)&Bs[cur][kk][64 + tx * 4];
#pragma unroll
      for (int i = 0; i < 8; ++i)
#pragma unroll
        for (int j = 0; j < 8; ++j) acc[i][j] += a[i] * b[j];
    }
    __syncthreads();
    cur ^= 1;
  }
#pragma unroll
  for (int ih = 0; ih < 2; ++ih)
#pragma unroll
    for (int i = 0; i < 4; ++i) {
      const size_t r = bm + ih * 64 + ty * 4 + i;
#pragma unroll
      for (int jh = 0; jh < 2; ++jh) {
        float4 v = {acc[ih * 4 + i][jh * 4 + 0], acc[ih * 4 + i][jh * 4 + 1],
                    acc[ih * 4 + i][jh * 4 + 2], acc[ih * 4 + i][jh * 4 + 3]};
        *(float4*)&Cp[r * N + bn + jh * 64 + tx * 4] = v;
      }
    }
}

// ---------------- q: sum split-K partials (4) + LN -> q12n (f32 + bf16) -----
__global__ void k_ln_q(const float* __restrict__ qpart, const float* __restrict__ qnw,
                       float* __restrict__ q12n, unsigned short* __restrict__ q12bf) {
  const int bid = blockIdx.x;  // b*2 + c
  const int lane = threadIdx.x;
  const int b = bid >> 1, c = bid & 1;
  float x[4] = {};
#pragma unroll
  for (int s = 0; s < 4; ++s) {
    const float4 p = *(const float4*)&qpart[(size_t)s * 4096 * 512 + (size_t)b * 512 + c * 256 + lane * 4];
    x[0] += p.x; x[1] += p.y; x[2] += p.z; x[3] += p.w;
  }
  float sm = x[0] + x[1] + x[2] + x[3];
  float sq = x[0] * x[0] + x[1] * x[1] + x[2] * x[2] + x[3] * x[3];
  sm = wave_sum(sm);
  sq = wave_sum(sq);
  const float mean = sm * (1.f / 256.f);
  const float rs = 1.f / sqrtf(sq * (1.f / 256.f) - mean * mean + 1e-5f);
  const float4 w4 = *(const float4*)&qnw[lane * 4];
  float4 o;
  o.x = (x[0] - mean) * rs * w4.x;
  o.y = (x[1] - mean) * rs * w4.y;
  o.z = (x[2] - mean) * rs * w4.z;
  o.w = (x[3] - mean) * rs * w4.w;
  const size_t base = (size_t)(c * 4096 + b) * 256 + lane * 4;
  *(float4*)&q12n[base] = o;
  ushort4 ob;
  ob.x = f2bf(o.x); ob.y = f2bf(o.y); ob.z = f2bf(o.z); ob.w = f2bf(o.w);
  *(ushort4*)&q12bf[base] = ob;
}

// ---------------- stage-1 top-48 prefilter on bf16 scores (16-bit keys) -----
__global__ void k_topk1(const unsigned short* __restrict__ s_r,
                        int* __restrict__ i1c, int* __restrict__ i2c) {
  const int bid = blockIdx.x;  // side*8192 + b*2 + h
  const int side = bid >> 13;
  const int bh = bid & 8191;
  const int b = bh >> 1, h = bh & 1;
  const int lane = threadIdx.x;
  const unsigned short* row = s_r + (size_t)(side * 4096 + b) * 2048 + h * 1024;
  unsigned int ku[16];
  {
    const uint4 a = *(const uint4*)&row[lane * 16];
    const uint4 bq = *(const uint4*)&row[lane * 16 + 8];
    const unsigned int words[8] = {a.x, a.y, a.z, a.w, bq.x, bq.y, bq.z, bq.w};
#pragma unroll
    for (int j = 0; j < 8; ++j) {
      const unsigned int lo = words[j] & 0xFFFFu;
      const unsigned int hi = words[j] >> 16;
      ku[2 * j] = lo ^ ((lo & 0x8000u) ? 0xFFFFu : 0x8000u);
      ku[2 * j + 1] = hi ^ ((hi & 0x8000u) ? 0xFFFFu : 0x8000u);
    }
  }
  unsigned int T = 0u;
  for (int bpos = 15; bpos >= 0; --bpos) {
    const unsigned int cand = T | (1u << bpos);
    int c = 0;
#pragma unroll
    for (int i = 0; i < 16; ++i) c += (int)__popcll(__ballot(ku[i] >= cand));
    if (c >= 48) T = cand;  // uniform
  }
  int cgt = 0, ceq = 0;
#pragma unroll
  for (int i = 0; i < 16; ++i) {
    cgt += (ku[i] > T) ? 1 : 0;
    ceq += (ku[i] == T) ? 1 : 0;
  }
  int pgt = cgt, peq = ceq;
#pragma unroll
  for (int o = 1; o < 64; o <<= 1) {
    const int t1 = __shfl_up(pgt, o, 64);
    const int t2 = __shfl_up(peq, o, 64);
    if (lane >= o) { pgt += t1; peq += t2; }
  }
  const int total_gt = __shfl(pgt, 63, 64);  // < 48
  const int need_eq = 48 - total_gt;
  int sgt = pgt - cgt;
  int seq = peq - ceq;
  int* iout = (side ? i2c : i1c) + bh * 48;
#pragma unroll
  for (int i = 0; i < 16; ++i) {
    const int idx = lane * 16 + i;
    if (ku[i] > T) {
      iout[sgt++] = idx;
    } else if (ku[i] == T) {
      if (seq < need_eq) iout[total_gt + seq] = idx;
      ++seq;
    }
  }
}

// ---------------- fused: exact rescore (48x2 sides) + top-32 + stage-2 ------
__global__ __launch_bounds__(512) void k_sel2(
    const float* __restrict__ q12n, const float* __restrict__ Bg,
    const int* __restrict__ i1c, const int* __restrict__ i2c,
    const float* __restrict__ tu, const float* __restrict__ tv,
    const float* __restrict__ tucker_core, const int* __restrict__ shuffle_index,
    float* __restrict__ w_out, int* __restrict__ sh_out) {
  __shared__ float qs[2][256];
  __shared__ int ssel[2][48];
  __shared__ float sc[2][48], sd0s[2][48], sd1s[2][48];
  __shared__ float sgx[2][32], sgy[2][32];
  __shared__ int si32[2][32];
  const int bh = blockIdx.x;  // b*2 + h
  const int b = bh >> 1, h = bh & 1;
  const int tid = threadIdx.x;
  if (tid < 128) {
    const int sd = tid >> 6, t = tid & 63;
    *(float4*)&qs[sd][t * 4] =
        *(const float4*)&q12n[(size_t)(sd * 4096 + b) * 256 + t * 4];
  } else if (tid < 224) {
    const int j = tid - 128;  // 0..95
    const int sd = (j >= 48) ? 1 : 0;
    const int jj = j - sd * 48;
    ssel[sd][jj] = (sd ? i2c : i1c)[bh * 48 + jj];
  }
  __syncthreads();
  const int w = tid >> 6;
  const int sd = (w >= 4) ? 1 : 0;
  const int local = tid - sd * 256;
  const int g = local >> 2, c4 = local & 3;
  if (g < 48) {
    const int sel = ssel[sd][g];
    const float* kbase = Bg + (size_t)((sd * 2048 + h * 1024 + sel) * 2) * 256;
    const float* qp = qs[sd];
    float d0 = 0.f, d1 = 0.f;
#pragma unroll
    for (int r = 0; r < 2; ++r) {
      const float* krow = kbase + r * 256;
      float px = 0.f, py = 0.f, pz = 0.f, pw = 0.f;
#pragma unroll
      for (int i = 0; i < 16; ++i) {
        const int e = (i * 4 + c4) * 4;  // 4-lane group covers one 64B line
        const float4 kv = *(const float4*)&krow[e];
        const float4 qv = *(const float4*)&qp[e];
        px += kv.x * qv.x;
        py += kv.y * qv.y;
        pz += kv.z * qv.z;
        pw += kv.w * qv.w;
      }
      float a = (px + py) + (pz + pw);
      a += __shfl_xor(a, 1, 64);
      a += __shfl_xor(a, 2, 64);
      if (r == 0) d0 = a; else d1 = a;
    }
    if (c4 == 0) {
      const float* uv = sd ? tv : tu;
      sd0s[sd][g] = d0;
      sd1s[sd][g] = d1;
      sc[sd][g] = d0 * uv[h * 2 + 0] + d1 * uv[h * 2 + 1];
    }
  }
  __syncthreads();
  if (w == 0 || w == 4) {
    const int s2 = (w == 4) ? 1 : 0;
    const int lane = tid & 63;
    const unsigned int kv = (lane < 48) ? f2key(sc[s2][lane]) : 0u;
    unsigned int T = 0u;
    for (int bpos = 31; bpos >= 0; --bpos) {
      const unsigned int cand = T | (1u << bpos);
      if ((int)__popcll(__ballot(kv >= cand)) >= 32) T = cand;
    }
    const unsigned long long mgt = __ballot(kv > T);
    const unsigned long long meq = __ballot((kv == T) && (lane < 48));
    const unsigned long long below = ((unsigned long long)1 << lane) - 1;
    const int total_gt = (int)__popcll(mgt);
    const int need = 32 - total_gt;
    int slot = -1;
    if (kv > T) {
      slot = (int)__popcll(mgt & below);
    } else if (kv == T && lane < 48) {
      const int r = (int)__popcll(meq & below);
      if (r < need) slot = total_gt + r;
    }
    if (slot >= 0) {
      si32[s2][slot] = ssel[s2][lane];
      sgx[s2][slot] = sd0s[s2][lane];
      sgy[s2][slot] = sd1s[s2][lane];
    }
  }
  __syncthreads();
  if (w == 0) {
    const int lane = tid;  // 0..63
    const float c00 = tucker_core[h * 4 + 0] + tucker_core[8 + h * 4 + 0];
    const float c01 = tucker_core[h * 4 + 1] + tucker_core[8 + h * 4 + 1];
    const float c10 = tucker_core[h * 4 + 2] + tucker_core[8 + h * 4 + 2];
    const float c11 = tucker_core[h * 4 + 3] + tucker_core[8 + h * 4 + 3];
    float sv[16];
    unsigned int ku[16];
    float m = -FLT_MAX;
#pragma unroll
    for (int i = 0; i < 16; ++i) {
      const int p = lane + (i << 6);
      const int k = p >> 5, l = p & 31;
      const float a0 = sgx[0][k] * c00 + sgy[0][k] * c10;
      const float a1 = sgx[0][k] * c01 + sgy[0][k] * c11;
      sv[i] = a0 * sgx[1][l] + a1 * sgy[1][l];
      ku[i] = f2key(sv[i]);
      m = fmaxf(m, sv[i]);
    }
#pragma unroll
    for (int o = 32; o; o >>= 1) m = fmaxf(m, __shfl_xor(m, o, 64));
    unsigned int T = 0u;
    for (int bpos = 31; bpos >= 0; --bpos) {
      const unsigned int cand = T | (1u << bpos);
      int c = 0;
#pragma unroll
      for (int i = 0; i < 16; ++i) c += (int)__popcll(__ballot(ku[i] >= cand));
      if (c >= 32) T = cand;
    }
    int cgt = 0, ceq = 0;
    float zp = 0.f;
#pragma unroll
    for (int i = 0; i < 16; ++i) {
      if (ku[i] > T) { ++cgt; zp += expf(sv[i] - m); }
      ceq += (ku[i] == T) ? 1 : 0;
    }
    int pgt = cgt, peq = ceq;
#pragma unroll
    for (int o = 1; o < 64; o <<= 1) {
      const int t1 = __shfl_up(pgt, o, 64);
      const int t2 = __shfl_up(peq, o, 64);
      if (lane >= o) { pgt += t1; peq += t2; }
    }
    const int total_gt = __shfl(pgt, 63, 64);
    const int need_eq = 32 - total_gt;
    const float eT = expf(key2f(T) - m);
    const float Z = wave_sum(zp) + (float)need_eq * eT;
    const float rZ = 1.f / Z;
    int sgt = pgt - cgt;
    int seq = peq - ceq;
    float* wp = w_out + bh * 32;
    int* shp = sh_out + bh * 32;
#pragma unroll
    for (int i = 0; i < 16; ++i) {
      int slot = -1;
      if (ku[i] > T) {
        slot = sgt++;
      } else if (ku[i] == T) {
        if (seq < need_eq) slot = total_gt + seq;
        ++seq;
      }
      if (slot >= 0) {
        const int p = lane + (i << 6);
        const int k = p >> 5, l = p & 31;
        const int ai = si32[0][k] * 1024 + si32[1][l];
        wp[slot] = expf(sv[i] - m) * rZ;
        shp[slot] = shuffle_index[ai];  // = (eidx<<18) | vidx
      }
    }
  }
}

// ---------------- weighted value gather/aggregate -> bf16 agg ---------------
__global__ __launch_bounds__(256) void k_agg(const float* __restrict__ w_out,
                                             const int* __restrict__ sh_out,
                                             const float* __restrict__ values,
                                             unsigned short* __restrict__ aggb) {
  __shared__ float acc[4][1024];
  const int b = blockIdx.x;
  const int tid = threadIdx.x;
  const int wave = tid >> 6, lane = tid & 63;
  for (int i = tid; i < 4096; i += 256) ((float*)acc)[i] = 0.f;
  __syncthreads();
  for (int j = wave; j < 64; j += 4) {
    const float wgt = w_out[b * 64 + j];
    const int sh = sh_out[b * 64 + j];
    const int vidx = sh & 0x3FFFF;
    const int e = sh >> 18;
    const float4 v = *(const float4*)&values[(size_t)vidx * 256 + lane * 4];
    float* dst = &acc[wave][e * 256 + lane * 4];
    dst[0] += wgt * v.x;
    dst[1] += wgt * v.y;
    dst[2] += wgt * v.z;
    dst[3] += wgt * v.w;
  }
  __syncthreads();
  for (int i = tid; i < 1024; i += 256)
    aggb[(size_t)b * 1024 + i] = f2bf(acc[0][i] + acc[1][i] + acc[2][i] + acc[3][i]);
}

// ---------------- transpose + convert f32 -> bf16 (for wv) ------------------
__global__ __launch_bounds__(256) void k_tcvt(const float* __restrict__ src,
                                              unsigned short* __restrict__ dst,
                                              int R, int C) {
  __shared__ float tile[64][65];
  const int br = blockIdx.x * 64;
  const int bc = blockIdx.y * 64;
  const int tid = threadIdx.x;
  for (int idx = tid; idx < 4096; idx += 256) {
    const int r = idx >> 6, c = idx & 63;
    tile[r][c] = src[(size_t)(br + r) * C + bc + c];
  }
  __syncthreads();
  for (int idx = tid; idx < 4096; idx += 256) {
    const int cc = idx >> 6, rr = idx & 63;
    dst[(size_t)(bc + cc) * R + br + rr] = f2bf(tile[rr][cc]);
  }
}

// ---------------- bf16 MFMA GEMM (scores -> bf16 out; final -> f32 out) -----
template <int BM, int BN, bool OBF>
__global__ __launch_bounds__(256) void k_mfma(const unsigned short* __restrict__ A,
                                              const unsigned short* __restrict__ Bt,
                                              void* __restrict__ Cv,
                                              int M, int N, int K,
                                              int bsk, int m_split) {
  constexpr int FM = BM / 32;
  constexpr int FN = BN / 32;
  __shared__ float4 As[BM * 4];
  __shared__ float4 Bs[BN * 4];
  const int tid = threadIdx.x;
  const int lane = tid & 63;
  const int w = tid >> 6;
  const int wr = w >> 1, wc = w & 1;
  const int bm = blockIdx.x * BM, bn = blockIdx.y * BN;
  const int bcol = bn + ((bm >= m_split) ? bsk : 0);
  f32x4 acc[FM][FN];
#pragma unroll
  for (int i = 0; i < FM; ++i)
#pragma unroll
    for (int j = 0; j < FN; ++j) acc[i][j] = 0.f;

  for (int k0 = 0; k0 < K; k0 += 32) {
#pragma unroll
    for (int u = 0; u < BM * 4 / 256; ++u) {
      const int q = tid + u * 256;
      const int m = q >> 2, c = q & 3;
      As[(m >> 4) * 64 + c * 16 + (m & 15)] =
          *(const float4*)&A[(size_t)(bm + m) * K + k0 + c * 8];
    }
#pragma unroll
    for (int u = 0; u < BN * 4 / 256; ++u) {
      const int q = tid + u * 256;
      const int n = q >> 2, c = q & 3;
      Bs[(n >> 4) * 64 + c * 16 + (n & 15)] =
          *(const float4*)&Bt[(size_t)(bcol + n) * K + k0 + c * 8];
    }
    __syncthreads();
    bf16x8 af[FM], bfr[FN];
#pragma unroll
    for (int i = 0; i < FM; ++i) af[i] = *(const bf16x8*)&As[(wr * FM + i) * 64 + lane];
#pragma unroll
    for (int j = 0; j < FN; ++j) bfr[j] = *(const bf16x8*)&Bs[(wc * FN + j) * 64 + lane];
#pragma unroll
    for (int i = 0; i < FM; ++i)
#pragma unroll
      for (int j = 0; j < FN; ++j)
        acc[i][j] = __builtin_amdgcn_mfma_f32_16x16x32_bf16(af[i], bfr[j], acc[i][j], 0, 0, 0);
    __syncthreads();
  }
#pragma unroll
  for (int i = 0; i < FM; ++i) {
    const int r0 = bm + (wr * FM + i) * 16 + (lane >> 4) * 4;
#pragma unroll
    for (int j = 0; j < FN; ++j) {
      const int cc = bn + (wc * FN + j) * 16 + (lane & 15);
#pragma unroll
      for (int v = 0; v < 4; ++v) {
        if (OBF)
          ((unsigned short*)Cv)[(size_t)(r0 + v) * N + cc] = f2bf(acc[i][j][v]);
        else
          ((float*)Cv)[(size_t)(r0 + v) * N + cc] = acc[i][j][v];
      }
    }
  }
}

// ---------------------------------------------------------------------------
extern "C" void kernel_launch(void* const* d_in, const int* in_sizes, int n_in,
                              void* d_out, int out_size, void* d_ws, size_t ws_size,
                              hipStream_t stream) {
  const float* hidden = (const float*)d_in[0];
  const float* wq     = (const float*)d_in[1];
  const float* qnw    = (const float*)d_in[2];
  const float* knw    = (const float*)d_in[3];
  const float* keys   = (const float*)d_in[4];
  const float* tcore  = (const float*)d_in[5];
  const float* tu     = (const float*)d_in[6];
  const float* tv     = (const float*)d_in[7];
  const float* values = (const float*)d_in[8];
  const float* wvm    = (const float*)d_in[9];
  const int*   shuf   = (const int*)d_in[10];
  float* out = (float*)d_out;

  char* ws = (char*)d_ws;
  size_t off = 0;
  auto alloc = [&](size_t bytes) -> void* {
    void* p = ws + off;
    off += (bytes + 255) & ~(size_t)255;
    return p;
  };
  unsigned short* Bctbf = (unsigned short*)alloc((size_t)4096 * 256 * 2);  // 2 MB
  float* Bg    = (float*)alloc((size_t)4096 * 512 * 4);                    // 8 MB
  float* q12n  = (float*)alloc((size_t)8192 * 256 * 4);                    // 8 MB
  unsigned short* q12bf = (unsigned short*)alloc((size_t)8192 * 256 * 2);  // 4 MB
  unsigned short* wvT  = (unsigned short*)alloc((size_t)2048 * 1024 * 2);  // 4 MB
  unsigned short* aggb = (unsigned short*)alloc((size_t)4096 * 1024 * 2);  // 8 MB
  int*   i1c = (int*)  alloc((size_t)8192 * 48 * 4);
  int*   i2c = (int*)  alloc((size_t)8192 * 48 * 4);
  float* wgt = (float*)alloc((size_t)8192 * 32 * 4);
  int*   sho = (int*)  alloc((size_t)8192 * 32 * 4);
  float* hiddenT = (float*)alloc((size_t)2048 * 4096 * 4);  // 32 MB
  float* big = (float*)alloc((size_t)8192 * 2048 * 4);      // 64 MB shared
  float* qpart = big;                          // 4 x 4096 x 512 f32 (32 MB)
  unsigned short* s_r = (unsigned short*)big;  // 8192 x 2048 bf16 (32 MB), after
  (void)ws_size; (void)in_sizes; (void)n_in; (void)out_size;

  // 1) keys -> Bg (raw keysn, f32) + Bctbf (u/v-combined, bf16)
  k_prep32<<<4096, 64, 0, stream>>>(keys, knw, tu, tv, Bctbf, Bg);
  // 2) wv -> bf16 transposed; hidden -> hiddenT
  k_tcvt<<<dim3(16, 32), 256, 0, stream>>>(wvm, wvT, 1024, 2048);
  k_tr32<<<dim3(64, 32), 256, 0, stream>>>(hidden, hiddenT, 4096, 2048);
  // 3) q projection, f32 split-K=4
  k_gemm32<4><<<dim3(32, 4, 4), 256, 0, stream>>>(
      hiddenT, 4096, wq, 512, 0, 1 << 30, qpart, 4096, 512, 2048);
  // 4) sum partials + LN -> q12n (f32) + q12bf (bf16)
  k_ln_q<<<8192, 64, 0, stream>>>(qpart, qnw, q12n, q12bf);
  // 5) prefilter score GEMM (bf16 MFMA, bf16 output)
  k_mfma<128, 128, true><<<dim3(64, 16), 256, 0, stream>>>(
      q12bf, Bctbf, s_r, 8192, 2048, 256, 2048, 4096);
  // 6) stage-1 top-48 prefilter (16-bit bisection)
  k_topk1<<<16384, 64, 0, stream>>>(s_r, i1c, i2c);
  // 7) fused exact rescore + top-32 + stage-2 -> wgt/sho
  k_sel2<<<8192, 512, 0, stream>>>(q12n, Bg, i1c, i2c, tu, tv, tcore, shuf,
                                   wgt, sho);
  // 8) weighted value gather -> bf16 agg
  k_agg<<<4096, 256, 0, stream>>>(wgt, sho, values, aggb);
  // 9) output projection (bf16 MFMA, f32 output)
  k_mfma<128, 128, false><<<dim3(32, 16), 256, 0, stream>>>(
      aggb, wvT, out, 4096, 2048, 1024, 0, 1 << 30);
}